// Round 1
// baseline (132.038 us; speedup 1.0000x reference)
//
#include <hip/hip_runtime.h>
#include <math.h>

#define LOG2E 1.4426950408889634f

typedef __attribute__((ext_vector_type(4))) float f32x4;
typedef __attribute__((ext_vector_type(8))) short bf16x8;

// ---------------- workspace offsets (bytes) ----------------
#define OFS_KR   0          // 8192 f32
#define OFS_LR   32768      // 8192 f32
#define OFS_S1   65536      // 1 f32 (+pad)
#define OFS_NXS  65792      // 8192 f32  (-||x_bf16||^2 * log2e)
#define OFS_NYS  98560      // 8192 f32
#define OFS_XB   131584     // 8192x128 bf16 (2 MB)
#define OFS_YB   2228736    // 8192x16 bf16 (256 KB)
#define WS_NEED  2490880

// ---------------- LDS offsets (bytes) ----------------
#define SM_AX    0          // 128 rows x 256 B (bf16, XOR-swizzled 16B units)
#define SM_BX    32768
#define SM_AY    65536      // 128 rows x 32 B (K=16)
#define SM_BY    69632
#define SM_NXSI  73728      // 128 f32 each
#define SM_NXSJ  74240
#define SM_NYSI  74752
#define SM_NYSJ  75264
#define SM_KRS   75776      // 128 f32 accumulators each
#define SM_LRS   76288
#define SM_KCS   76800
#define SM_LCS   77312
#define SM_S1    77824
#define SM_BYTES 77840

__device__ __forceinline__ unsigned short bf16rne(float f) {
  unsigned u = __float_as_uint(f);
  unsigned r = u + 0x7FFFu + ((u >> 16) & 1u);
  return (unsigned short)(r >> 16);
}
__device__ __forceinline__ float bf16tof(unsigned short h) {
  return __uint_as_float(((unsigned)h) << 16);
}

// ---- prep x: fp32 [8192][128] -> bf16 + row norm (pre-scaled, negated) ----
__global__ void prep_x(const float* __restrict__ x, unsigned* __restrict__ xb,
                       float* __restrict__ nxs) {
  const int wid = threadIdx.x >> 6, lane = threadIdx.x & 63;
  const int row = blockIdx.x * 4 + wid;
  const float2 v = ((const float2*)(x + (size_t)row * 128))[lane];
  const unsigned short h0 = bf16rne(v.x), h1 = bf16rne(v.y);
  const float f0 = bf16tof(h0), f1 = bf16tof(h1);
  float s = f0 * f0 + f1 * f1;
  xb[row * 64 + lane] = (unsigned)h0 | ((unsigned)h1 << 16);
#pragma unroll
  for (int m = 1; m < 64; m <<= 1) s += __shfl_xor(s, m);
  if (lane == 0) nxs[row] = -s * LOG2E;
}

// ---- prep y: fp32 [8192][16] -> bf16 + row norm ----
__global__ void prep_y(const float* __restrict__ y, unsigned* __restrict__ yb,
                       float* __restrict__ nys) {
  const int row = blockIdx.x * 256 + threadIdx.x;
  const float* py = y + (size_t)row * 16;
  float s = 0.f;
  unsigned w[8];
#pragma unroll
  for (int c = 0; c < 8; ++c) {
    const float a = py[2 * c], b = py[2 * c + 1];
    const unsigned short ha = bf16rne(a), hb = bf16rne(b);
    const float fa = bf16tof(ha), fb = bf16tof(hb);
    s += fa * fa + fb * fb;
    w[c] = (unsigned)ha | ((unsigned)hb << 16);
  }
  uint4* dst = ((uint4*)yb) + row * 2;
  dst[0] = make_uint4(w[0], w[1], w[2], w[3]);
  dst[1] = make_uint4(w[4], w[5], w[6], w[7]);
  nys[row] = -s * LOG2E;
}

// ---- pair kernel: upper-triangular 128x128 tiles ----
__global__ __launch_bounds__(256, 2) void hsic_pair(
    const char* __restrict__ xb, const char* __restrict__ yb,
    const float* __restrict__ nxs, const float* __restrict__ nys,
    float* __restrict__ kr, float* __restrict__ lr, float* __restrict__ s1g) {
  extern __shared__ char sm[];
  const int tid = threadIdx.x;
  const int lane = tid & 63, wid = tid >> 6;
  const int q = lane >> 4, n16 = lane & 15;
  const int qr = wid >> 1, qc = wid & 1;

  // decode flat block index -> (bi, bj), bi <= bj, 64 tiles/dim
  const int t = blockIdx.x;
  int bi = (int)((129.0 - sqrt(16641.0 - 8.0 * (double)t)) * 0.5);
  if (bi < 0) bi = 0;
  if (bi > 63) bi = 63;
  while ((bi + 1) * (128 - bi) / 2 <= t) ++bi;
  while (bi * (129 - bi) / 2 > t) --bi;
  const int bj = bi + (t - bi * (129 - bi) / 2);
  const bool diag = (bi == bj);

  float* krs = (float*)(sm + SM_KRS);
  float* lrs = (float*)(sm + SM_LRS);
  float* kcs = (float*)(sm + SM_KCS);
  float* lcs = (float*)(sm + SM_LCS);

  if (tid < 128) {
    krs[tid] = 0.f; lrs[tid] = 0.f; kcs[tid] = 0.f; lcs[tid] = 0.f;
    ((float*)(sm + SM_NXSI))[tid] = nxs[bi * 128 + tid];
    ((float*)(sm + SM_NXSJ))[tid] = nxs[bj * 128 + tid];
    ((float*)(sm + SM_NYSI))[tid] = nys[bi * 128 + tid];
    ((float*)(sm + SM_NYSJ))[tid] = nys[bj * 128 + tid];
  }
  if (tid == 0) *(float*)(sm + SM_S1) = 0.f;

  // stage x tiles (16B-unit XOR swizzle: phys unit = u ^ (row & 15))
#pragma unroll
  for (int it = 0; it < 8; ++it) {
    const int fu = it * 256 + tid, r = fu >> 4, u = fu & 15, p = u ^ (r & 15);
    *(uint4*)(sm + SM_AX + r * 256 + p * 16) =
        *(const uint4*)(xb + (bi * 128 + r) * 256 + u * 16);
  }
  if (!diag) {
#pragma unroll
    for (int it = 0; it < 8; ++it) {
      const int fu = it * 256 + tid, r = fu >> 4, u = fu & 15, p = u ^ (r & 15);
      *(uint4*)(sm + SM_BX + r * 256 + p * 16) =
          *(const uint4*)(xb + (bj * 128 + r) * 256 + u * 16);
    }
  }
  { // y tiles: 128 rows x 32 B, phys unit = u ^ (row & 1)
    const int r = tid >> 1, u = tid & 1, p = u ^ (r & 1);
    *(uint4*)(sm + SM_AY + r * 32 + p * 16) =
        *(const uint4*)(yb + (bi * 128 + r) * 32 + u * 16);
    if (!diag)
      *(uint4*)(sm + SM_BY + r * 32 + p * 16) =
          *(const uint4*)(yb + (bj * 128 + r) * 32 + u * 16);
  }
  __syncthreads();

  const char* AXp = sm + SM_AX;
  const char* BXp = diag ? (sm + SM_AX) : (sm + SM_BX);
  const char* AYp = sm + SM_AY;
  const char* BYp = diag ? (sm + SM_AY) : (sm + SM_BY);

  const f32x4 zf = {0.f, 0.f, 0.f, 0.f};
  f32x4 accx[4][4], accy[4][4];
#pragma unroll
  for (int a = 0; a < 4; ++a)
#pragma unroll
    for (int b = 0; b < 4; ++b) { accx[a][b] = zf; accy[a][b] = zf; }

  const bf16x8 zb = {0, 0, 0, 0, 0, 0, 0, 0};

  // ---- y Gram (K=16; lanes q>=2 carry zeros in the K=32 MFMA) ----
  bf16x8 byf[4];
#pragma unroll
  for (int tj = 0; tj < 4; ++tj) {
    bf16x8 v = zb;
    if (q < 2) {
      const int row = qc * 64 + tj * 16 + n16;
      const int p = q ^ (row & 1);
      v = *(const bf16x8*)(BYp + row * 32 + p * 16);
    }
    byf[tj] = v;
  }
#pragma unroll
  for (int ti = 0; ti < 4; ++ti) {
    bf16x8 av = zb;
    if (q < 2) {
      const int row = qr * 64 + ti * 16 + n16;
      const int p = q ^ (row & 1);
      av = *(const bf16x8*)(AYp + row * 32 + p * 16);
    }
#pragma unroll
    for (int tj = 0; tj < 4; ++tj)
      accy[ti][tj] = __builtin_amdgcn_mfma_f32_16x16x32_bf16(av, byf[tj], accy[ti][tj], 0, 0, 0);
  }

  // ---- x Gram (K=128, 4 k-steps) ----
#pragma unroll
  for (int ks = 0; ks < 4; ++ks) {
    bf16x8 bxf[4];
#pragma unroll
    for (int tj = 0; tj < 4; ++tj) {
      const int row = qc * 64 + tj * 16 + n16;
      const int p = (ks * 4 + q) ^ n16;
      bxf[tj] = *(const bf16x8*)(BXp + row * 256 + p * 16);
    }
#pragma unroll
    for (int ti = 0; ti < 4; ++ti) {
      const int row = qr * 64 + ti * 16 + n16;
      const int p = (ks * 4 + q) ^ n16;
      const bf16x8 av = *(const bf16x8*)(AXp + row * 256 + p * 16);
#pragma unroll
      for (int tj = 0; tj < 4; ++tj)
        accx[ti][tj] = __builtin_amdgcn_mfma_f32_16x16x32_bf16(av, bxf[tj], accx[ti][tj], 0, 0, 0);
    }
  }

  // ---- epilogue: K = exp2(2*log2e*G + nxs_i + nxs_j), same for L ----
  const float T2 = 2.0f * LOG2E;
  float s1 = 0.f;
  float kcol[4] = {0.f, 0.f, 0.f, 0.f}, lcol[4] = {0.f, 0.f, 0.f, 0.f};
#pragma unroll
  for (int ti = 0; ti < 4; ++ti) {
    const int ibase = qr * 64 + ti * 16 + q * 4;  // rows ibase..ibase+3 (reg r)
    const f32x4 nxsi = *(const f32x4*)(sm + SM_NXSI + ibase * 4);
    const f32x4 nysi = *(const f32x4*)(sm + SM_NYSI + ibase * 4);
    float krow[4] = {0.f, 0.f, 0.f, 0.f}, lrow[4] = {0.f, 0.f, 0.f, 0.f};
#pragma unroll
    for (int tj = 0; tj < 4; ++tj) {
      const int jj = qc * 64 + tj * 16 + n16;  // col index (lane&15)
      const float nxsj = ((const float*)(sm + SM_NXSJ))[jj];
      const float nysj = ((const float*)(sm + SM_NYSJ))[jj];
#pragma unroll
      for (int r = 0; r < 4; ++r) {
        const float K = exp2f(fmaf(T2, accx[ti][tj][r], nxsi[r] + nxsj));
        const float L = exp2f(fmaf(T2, accy[ti][tj][r], nysi[r] + nysj));
        s1 = fmaf(K, L, s1);
        krow[r] += K; lrow[r] += L;
        kcol[tj] += K; lcol[tj] += L;
      }
    }
#pragma unroll
    for (int r = 0; r < 4; ++r) {  // row sums: reduce over the 16-lane col group
      float k = krow[r], l = lrow[r];
#pragma unroll
      for (int mm = 1; mm <= 8; mm <<= 1) { k += __shfl_xor(k, mm); l += __shfl_xor(l, mm); }
      if (n16 == 0) { atomicAdd(&krs[ibase + r], k); atomicAdd(&lrs[ibase + r], l); }
    }
  }
#pragma unroll
  for (int tj = 0; tj < 4; ++tj) {  // col sums: reduce over q groups
    float k = kcol[tj], l = lcol[tj];
    k += __shfl_xor(k, 16); l += __shfl_xor(l, 16);
    k += __shfl_xor(k, 32); l += __shfl_xor(l, 32);
    if (q == 0) {
      const int jj = qc * 64 + tj * 16 + n16;
      atomicAdd(&kcs[jj], k); atomicAdd(&lcs[jj], l);
    }
  }
#pragma unroll
  for (int mm = 1; mm < 64; mm <<= 1) s1 += __shfl_xor(s1, mm);
  if (lane == 0) atomicAdd((float*)(sm + SM_S1), s1);
  __syncthreads();

  if (tid < 128) {
    atomicAdd(&kr[bi * 128 + tid], krs[tid]);
    atomicAdd(&lr[bi * 128 + tid], lrs[tid]);
    if (!diag) {
      atomicAdd(&kr[bj * 128 + tid], kcs[tid]);
      atomicAdd(&lr[bj * 128 + tid], lcs[tid]);
    }
  }
  if (tid == 0)
    atomicAdd(s1g, (*(float*)(sm + SM_S1)) * (diag ? 1.0f : 2.0f));
}

// ---- finalize: hsic = (S1 - (2/m) sum kr*lr + SK*SL/m^2) / (m-1)^2 ----
__global__ void finalize(const float* __restrict__ kr, const float* __restrict__ lr,
                         const float* __restrict__ s1g, float* __restrict__ out) {
  __shared__ double sh[3][4];
  const int tid = threadIdx.x, lane = tid & 63, wid = tid >> 6;
  double c = 0.0, sk = 0.0, sl = 0.0;
  for (int i = tid; i < 8192; i += 256) {
    const double k = (double)kr[i], l = (double)lr[i];
    c += k * l; sk += k; sl += l;
  }
#pragma unroll
  for (int mm = 1; mm < 64; mm <<= 1) {
    c += __shfl_xor(c, mm); sk += __shfl_xor(sk, mm); sl += __shfl_xor(sl, mm);
  }
  if (lane == 0) { sh[0][wid] = c; sh[1][wid] = sk; sh[2][wid] = sl; }
  __syncthreads();
  if (tid == 0) {
    c = sh[0][0] + sh[0][1] + sh[0][2] + sh[0][3];
    sk = sh[1][0] + sh[1][1] + sh[1][2] + sh[1][3];
    sl = sh[2][0] + sh[2][1] + sh[2][2] + sh[2][3];
    const double m = 8192.0;
    const double s1 = (double)(*s1g);
    const double v = (s1 - (2.0 / m) * c + sk * sl / (m * m)) / ((m - 1.0) * (m - 1.0));
    *out = (float)v;
  }
}

extern "C" void kernel_launch(void* const* d_in, const int* in_sizes, int n_in,
                              void* d_out, int out_size, void* d_ws, size_t ws_size,
                              hipStream_t stream) {
  const float* x = (const float*)d_in[0];  // [8192,128] fp32
  const float* y = (const float*)d_in[1];  // [8192,16]  fp32
  float* out = (float*)d_out;
  char* ws = (char*)d_ws;

  float* kr = (float*)(ws + OFS_KR);
  float* lr = (float*)(ws + OFS_LR);
  float* s1 = (float*)(ws + OFS_S1);
  float* nxs = (float*)(ws + OFS_NXS);
  float* nys = (float*)(ws + OFS_NYS);
  unsigned* xb = (unsigned*)(ws + OFS_XB);
  unsigned* yb = (unsigned*)(ws + OFS_YB);

  // zero kr, lr, S1 (ws is poisoned 0xAA before every launch)
  hipMemsetAsync(ws, 0, OFS_S1 + 16, stream);

  prep_x<<<2048, 256, 0, stream>>>(x, xb, nxs);
  prep_y<<<32, 256, 0, stream>>>(y, yb, nys);
  hsic_pair<<<2080, 256, SM_BYTES, stream>>>((const char*)xb, (const char*)yb,
                                             nxs, nys, kr, lr, s1);
  finalize<<<1, 256, 0, stream>>>(kr, lr, s1, out);
}

// Round 2
// 129.344 us; speedup vs baseline: 1.0208x; 1.0208x over previous
//
#include <hip/hip_runtime.h>
#include <math.h>

#define LOG2E 1.4426950408889634f

typedef __attribute__((ext_vector_type(4))) float f32x4;
typedef __attribute__((ext_vector_type(8))) short bf16x8;

// ---------------- workspace offsets (bytes) ----------------
#define OFS_KR   0          // 8192 f32
#define OFS_LR   32768      // 8192 f32
#define OFS_S1   65536      // 1 f32 (+pad)
#define OFS_NXS  65792      // 8192 f32  (-||x_bf16||^2 * log2e)
#define OFS_NYS  98560      // 8192 f32
#define OFS_XB   131584     // 8192x128 bf16 (2 MB)
#define OFS_YB   2228736    // 8192x16 bf16 (256 KB)

// ---------------- LDS offsets (bytes) ----------------
#define SM_AX    0          // 128 rows x 256 B (bf16, XOR-swizzled 16B units)
#define SM_BX    32768
#define SM_NXSI  65536      // 128 f32 each
#define SM_NXSJ  66048
#define SM_NYSI  66560
#define SM_NYSJ  67072
#define SM_KRS   67584      // 128 f32 accumulators each
#define SM_LRS   68096
#define SM_KCS   68608
#define SM_LCS   69120
#define SM_S1    69632
#define SM_BYTES 69648

__device__ __forceinline__ unsigned short bf16rne(float f) {
  unsigned u = __float_as_uint(f);
  unsigned r = u + 0x7FFFu + ((u >> 16) & 1u);
  return (unsigned short)(r >> 16);
}
__device__ __forceinline__ float bf16tof(unsigned short h) {
  return __uint_as_float(((unsigned)h) << 16);
}
__device__ __forceinline__ float fexp2(float x) {
#if __has_builtin(__builtin_amdgcn_exp2f)
  return __builtin_amdgcn_exp2f(x);   // v_exp_f32; args here are <= 0, exact enough
#else
  return exp2f(x);
#endif
}

// ---- fused prep: bf16-convert x,y + row norms + zero kr/lr/S1 ----
__global__ void prep(const float* __restrict__ x, const float* __restrict__ y,
                     unsigned* __restrict__ xb, unsigned* __restrict__ yb,
                     float* __restrict__ nxs, float* __restrict__ nys,
                     float* __restrict__ kr, float* __restrict__ lr,
                     float* __restrict__ s1) {
  const int b = blockIdx.x;
  if (b < 2048) {
    // --- x rows 4b..4b+3 ---
    const int wid = threadIdx.x >> 6, lane = threadIdx.x & 63;
    const int row = b * 4 + wid;
    const float2 v = ((const float2*)(x + (size_t)row * 128))[lane];
    const unsigned short h0 = bf16rne(v.x), h1 = bf16rne(v.y);
    const float f0 = bf16tof(h0), f1 = bf16tof(h1);
    float s = f0 * f0 + f1 * f1;
    xb[row * 64 + lane] = (unsigned)h0 | ((unsigned)h1 << 16);
#pragma unroll
    for (int m = 1; m < 64; m <<= 1) s += __shfl_xor(s, m);
    if (lane == 0) nxs[row] = -s * LOG2E;
    if (threadIdx.x < 4) { kr[b * 4 + threadIdx.x] = 0.f; lr[b * 4 + threadIdx.x] = 0.f; }
    if (b == 0 && threadIdx.x == 4) *s1 = 0.f;
  } else {
    // --- y rows ---
    const int row = (b - 2048) * 256 + threadIdx.x;
    const float* py = y + (size_t)row * 16;
    float s = 0.f;
    unsigned w[8];
#pragma unroll
    for (int c = 0; c < 8; ++c) {
      const float a = py[2 * c], bb = py[2 * c + 1];
      const unsigned short ha = bf16rne(a), hb = bf16rne(bb);
      const float fa = bf16tof(ha), fb = bf16tof(hb);
      s += fa * fa + fb * fb;
      w[c] = (unsigned)ha | ((unsigned)hb << 16);
    }
    uint4* dst = ((uint4*)yb) + row * 2;
    dst[0] = make_uint4(w[0], w[1], w[2], w[3]);
    dst[1] = make_uint4(w[4], w[5], w[6], w[7]);
    nys[row] = -s * LOG2E;
  }
}

// ---- pair kernel: upper-triangular 128x128 tiles, 512 threads (2x4 waves) ----
__global__ __launch_bounds__(512, 4) void hsic_pair(
    const char* __restrict__ xb, const char* __restrict__ yb,
    const float* __restrict__ nxs, const float* __restrict__ nys,
    float* __restrict__ kr, float* __restrict__ lr, float* __restrict__ s1g) {
  extern __shared__ char sm[];
  const int tid = threadIdx.x;
  const int lane = tid & 63, wid = tid >> 6;
  const int q = lane >> 4, n16 = lane & 15;
  const int qr = wid >> 2, qc = wid & 3;   // wave computes rows [qr*64,+64) x cols [qc*32,+32)

  // decode flat block index -> (bi, bj), bi <= bj, 64 tiles/dim
  const int t = blockIdx.x;
  int bi = (int)((129.0 - sqrt(16641.0 - 8.0 * (double)t)) * 0.5);
  if (bi < 0) bi = 0;
  if (bi > 63) bi = 63;
  while ((bi + 1) * (128 - bi) / 2 <= t) ++bi;
  while (bi * (129 - bi) / 2 > t) --bi;
  const int bj = bi + (t - bi * (129 - bi) / 2);
  const bool diag = (bi == bj);

  float* krs = (float*)(sm + SM_KRS);
  float* lrs = (float*)(sm + SM_LRS);
  float* kcs = (float*)(sm + SM_KCS);
  float* lcs = (float*)(sm + SM_LCS);

  if (tid < 128) {
    krs[tid] = 0.f; lrs[tid] = 0.f; kcs[tid] = 0.f; lcs[tid] = 0.f;
    ((float*)(sm + SM_NXSI))[tid] = nxs[bi * 128 + tid];
    ((float*)(sm + SM_NXSJ))[tid] = nxs[bj * 128 + tid];
    ((float*)(sm + SM_NYSI))[tid] = nys[bi * 128 + tid];
    ((float*)(sm + SM_NYSJ))[tid] = nys[bj * 128 + tid];
  }
  if (tid == 0) *(float*)(sm + SM_S1) = 0.f;

  // stage x tiles (16B-unit XOR swizzle: phys unit = u ^ (row & 15))
#pragma unroll
  for (int it = 0; it < 4; ++it) {
    const int fu = it * 512 + tid, r = fu >> 4, u = fu & 15, p = u ^ (r & 15);
    *(uint4*)(sm + SM_AX + r * 256 + p * 16) =
        *(const uint4*)(xb + (bi * 128 + r) * 256 + u * 16);
  }
  if (!diag) {
#pragma unroll
    for (int it = 0; it < 4; ++it) {
      const int fu = it * 512 + tid, r = fu >> 4, u = fu & 15, p = u ^ (r & 15);
      *(uint4*)(sm + SM_BX + r * 256 + p * 16) =
          *(const uint4*)(xb + (bj * 128 + r) * 256 + u * 16);
    }
  }

  const f32x4 zf = {0.f, 0.f, 0.f, 0.f};
  f32x4 accx[4][2], accy[4][2];
#pragma unroll
  for (int a = 0; a < 4; ++a)
#pragma unroll
    for (int b = 0; b < 2; ++b) { accx[a][b] = zf; accy[a][b] = zf; }

  const bf16x8 zb = {0, 0, 0, 0, 0, 0, 0, 0};

  // ---- y Gram straight from global (coalesced 32B rows), before the barrier
  //      K=16: lanes q>=2 carry zeros in the K=32 MFMA ----
  const int bir = bi * 128, bjr = bj * 128;
  {
    bf16x8 byf[2];
#pragma unroll
    for (int tj = 0; tj < 2; ++tj) {
      bf16x8 v = zb;
      if (q < 2)
        v = *(const bf16x8*)(yb + (size_t)(bjr + qc * 32 + tj * 16 + n16) * 32 + q * 16);
      byf[tj] = v;
    }
#pragma unroll
    for (int ti = 0; ti < 4; ++ti) {
      bf16x8 av = zb;
      if (q < 2)
        av = *(const bf16x8*)(yb + (size_t)(bir + qr * 64 + ti * 16 + n16) * 32 + q * 16);
#pragma unroll
      for (int tj = 0; tj < 2; ++tj)
        accy[ti][tj] = __builtin_amdgcn_mfma_f32_16x16x32_bf16(av, byf[tj], accy[ti][tj], 0, 0, 0);
    }
  }
  __syncthreads();

  const char* BXp = diag ? (sm + SM_AX) : (sm + SM_BX);

  // ---- x Gram (K=128, 4 k-steps) ----
#pragma unroll
  for (int ks = 0; ks < 4; ++ks) {
    const int pu = (ks * 4 + q) ^ n16;
    bf16x8 bxf[2], axf[4];
#pragma unroll
    for (int tj = 0; tj < 2; ++tj)
      bxf[tj] = *(const bf16x8*)(BXp + (qc * 32 + tj * 16 + n16) * 256 + pu * 16);
#pragma unroll
    for (int ti = 0; ti < 4; ++ti)
      axf[ti] = *(const bf16x8*)(sm + SM_AX + (qr * 64 + ti * 16 + n16) * 256 + pu * 16);
#pragma unroll
    for (int ti = 0; ti < 4; ++ti)
#pragma unroll
      for (int tj = 0; tj < 2; ++tj)
        accx[ti][tj] = __builtin_amdgcn_mfma_f32_16x16x32_bf16(axf[ti], bxf[tj], accx[ti][tj], 0, 0, 0);
  }

  // ---- epilogue: K = exp2(2*log2e*G + nxs_i + nxs_j), same for L ----
  const float T2 = 2.0f * LOG2E;
  float s1 = 0.f;
  float nxsj[2], nysj[2];
#pragma unroll
  for (int tj = 0; tj < 2; ++tj) {
    const int jj = qc * 32 + tj * 16 + n16;
    nxsj[tj] = ((const float*)(sm + SM_NXSJ))[jj];
    nysj[tj] = ((const float*)(sm + SM_NYSJ))[jj];
  }
  float kcol[2] = {0.f, 0.f}, lcol[2] = {0.f, 0.f};
#pragma unroll
  for (int ti = 0; ti < 4; ++ti) {
    const int ibase = qr * 64 + ti * 16 + q * 4;  // rows ibase..ibase+3 (reg r)
    const f32x4 nxsi = *(const f32x4*)(sm + SM_NXSI + ibase * 4);
    const f32x4 nysi = *(const f32x4*)(sm + SM_NYSI + ibase * 4);
    float krow[4] = {0.f, 0.f, 0.f, 0.f}, lrow[4] = {0.f, 0.f, 0.f, 0.f};
#pragma unroll
    for (int tj = 0; tj < 2; ++tj) {
#pragma unroll
      for (int r = 0; r < 4; ++r) {
        const float K = fexp2(fmaf(T2, accx[ti][tj][r], nxsi[r] + nxsj[tj]));
        const float L = fexp2(fmaf(T2, accy[ti][tj][r], nysi[r] + nysj[tj]));
        s1 = fmaf(K, L, s1);
        krow[r] += K; lrow[r] += L;
        kcol[tj] += K; lcol[tj] += L;
      }
    }
#pragma unroll
    for (int r = 0; r < 4; ++r) {  // row sums: reduce over the 16-lane col group
      float k = krow[r], l = lrow[r];
#pragma unroll
      for (int mm = 1; mm <= 8; mm <<= 1) { k += __shfl_xor(k, mm); l += __shfl_xor(l, mm); }
      if (n16 == 0) { atomicAdd(&krs[ibase + r], k); atomicAdd(&lrs[ibase + r], l); }
    }
  }
#pragma unroll
  for (int tj = 0; tj < 2; ++tj) {  // col sums: reduce over q groups (and qr waves via LDS)
    float k = kcol[tj], l = lcol[tj];
    k += __shfl_xor(k, 16); l += __shfl_xor(l, 16);
    k += __shfl_xor(k, 32); l += __shfl_xor(l, 32);
    if (q == 0) {
      const int jj = qc * 32 + tj * 16 + n16;
      atomicAdd(&kcs[jj], k); atomicAdd(&lcs[jj], l);
    }
  }
#pragma unroll
  for (int mm = 1; mm < 64; mm <<= 1) s1 += __shfl_xor(s1, mm);
  if (lane == 0) atomicAdd((float*)(sm + SM_S1), s1);
  __syncthreads();

  if (tid < 128) {
    atomicAdd(&kr[bi * 128 + tid], krs[tid]);
    atomicAdd(&lr[bi * 128 + tid], lrs[tid]);
    if (!diag) {
      atomicAdd(&kr[bj * 128 + tid], kcs[tid]);
      atomicAdd(&lr[bj * 128 + tid], lcs[tid]);
    }
  }
  if (tid == 0)
    atomicAdd(s1g, (*(float*)(sm + SM_S1)) * (diag ? 1.0f : 2.0f));
}

// ---- finalize: hsic = (S1 - (2/m) sum kr*lr + SK*SL/m^2) / (m-1)^2 ----
__global__ void finalize(const float* __restrict__ kr, const float* __restrict__ lr,
                         const float* __restrict__ s1g, float* __restrict__ out) {
  __shared__ double sh[3][4];
  const int tid = threadIdx.x, lane = tid & 63, wid = tid >> 6;
  double c = 0.0, sk = 0.0, sl = 0.0;
  for (int i = tid; i < 8192; i += 256) {
    const double k = (double)kr[i], l = (double)lr[i];
    c += k * l; sk += k; sl += l;
  }
#pragma unroll
  for (int mm = 1; mm < 64; mm <<= 1) {
    c += __shfl_xor(c, mm); sk += __shfl_xor(sk, mm); sl += __shfl_xor(sl, mm);
  }
  if (lane == 0) { sh[0][wid] = c; sh[1][wid] = sk; sh[2][wid] = sl; }
  __syncthreads();
  if (tid == 0) {
    c = sh[0][0] + sh[0][1] + sh[0][2] + sh[0][3];
    sk = sh[1][0] + sh[1][1] + sh[1][2] + sh[1][3];
    sl = sh[2][0] + sh[2][1] + sh[2][2] + sh[2][3];
    const double m = 8192.0;
    const double s1 = (double)(*s1g);
    const double v = (s1 - (2.0 / m) * c + sk * sl / (m * m)) / ((m - 1.0) * (m - 1.0));
    *out = (float)v;
  }
}

extern "C" void kernel_launch(void* const* d_in, const int* in_sizes, int n_in,
                              void* d_out, int out_size, void* d_ws, size_t ws_size,
                              hipStream_t stream) {
  const float* x = (const float*)d_in[0];  // [8192,128] fp32
  const float* y = (const float*)d_in[1];  // [8192,16]  fp32
  float* out = (float*)d_out;
  char* ws = (char*)d_ws;

  float* kr = (float*)(ws + OFS_KR);
  float* lr = (float*)(ws + OFS_LR);
  float* s1 = (float*)(ws + OFS_S1);
  float* nxs = (float*)(ws + OFS_NXS);
  float* nys = (float*)(ws + OFS_NYS);
  unsigned* xb = (unsigned*)(ws + OFS_XB);
  unsigned* yb = (unsigned*)(ws + OFS_YB);

  prep<<<2080, 256, 0, stream>>>(x, y, xb, yb, nxs, nys, kr, lr, s1);
  hsic_pair<<<2080, 512, SM_BYTES, stream>>>((const char*)xb, (const char*)yb,
                                             nxs, nys, kr, lr, s1);
  finalize<<<1, 256, 0, stream>>>(kr, lr, s1, out);
}